// Round 1
// baseline (12649.039 us; speedup 1.0000x reference)
//
#include <hip/hip_runtime.h>

#define NT 256
#define BB 128
#define BT 100
#define DZc 64
#define DAc 32
#define DUc 8
#define KMIX 8
#define DOBSc 16
#define HG 128
#define DINc 56   // DA + DOBS + DU

// flat element offsets into d_out (return order of the reference tuple)
#define O_ZFILT   0LL
#define O_PFILT   819200LL
#define O_ZPRED   53248000LL
#define O_AFILT   54067200LL
#define O_APRED   54476800LL
#define O_PPRED   54886400LL
#define O_ALPHA   107315200LL
#define O_ASEQ    107417600LL
#define O_BSEQ    159846400LL
#define O_CSEQ    166400000LL
#define O_ZMEAN   192614400LL
#define O_LTRIL   193433600LL
#define O_SPRED   245862400LL

struct SMem {
    float P[DZc][DZc + 1];    // P_pred carry -> raw -> P_filt -> raw2 -> P_pred
    float A[DZc][DZc + 1];    // mixed A
    float Wk[DZc][DZc + 1];   // temp: P@IKC^T, then A@P_filt
    float IKC[DZc][DZc + 1];
    float Qm[DZc][DZc + 1];   // Q cached
    float C[DAc][DZc + 1];    // mixed C
    float CP[DAc][DZc + 1];   // C@P, then X = S^{-1} C P  (= Kg^T / mk)
    float KR[DZc][DAc + 1];   // Kg @ R
    float S[DAc][DAc + 1];    // innovation cov -> chol factor
    float Rm[DAc][DAc + 1];   // R cached
    float Bm[DZc][DUc];       // mixed B
    float z[DZc], zp[DZc], zn[DZc];
    float h[HG], hn[HG];
    float gi[3 * HG], gh[3 * HG];
    float x[DINc + 8];
    float ak[DAc], ahat[DAc], rvec[DAc];
    float u[DUc];
    float alpha[KMIX];
    float mk;
};

__device__ __forceinline__ void gru_mix(SMem& s, int tid,
    const float* __restrict__ W_ih, const float* __restrict__ W_hh,
    const float* __restrict__ b_ih, const float* __restrict__ b_hh,
    const float* __restrict__ W_out, const float* __restrict__ b_out,
    const float* __restrict__ A_mats, const float* __restrict__ B_mats,
    const float* __restrict__ C_mats)
{
    // (a) gi = W_ih x + b_ih ; gh = W_hh h + b_hh   (384 gates)
    for (int g = tid; g < 3 * HG; g += NT) {
        float acc = b_ih[g];
        const float* wr = W_ih + (size_t)g * DINc;
        #pragma unroll
        for (int d = 0; d < DINc; ++d) acc += wr[d] * s.x[d];
        s.gi[g] = acc;
        float acc2 = b_hh[g];
        const float* wr2 = W_hh + (size_t)g * HG;
        #pragma unroll 8
        for (int d = 0; d < HG; ++d) acc2 += wr2[d] * s.h[d];
        s.gh[g] = acc2;
    }
    __syncthreads();
    // (b) gates
    for (int i = tid; i < HG; i += NT) {
        float r  = 1.f / (1.f + expf(-(s.gi[i] + s.gh[i])));
        float zg = 1.f / (1.f + expf(-(s.gi[HG + i] + s.gh[HG + i])));
        float n  = tanhf(s.gi[2 * HG + i] + r * s.gh[2 * HG + i]);
        s.hn[i] = (1.f - zg) * n + zg * s.h[i];
    }
    __syncthreads();
    // (c) h = hn ; logits
    for (int i = tid; i < HG; i += NT) s.h[i] = s.hn[i];
    if (tid < KMIX) {
        float acc = b_out[tid];
        const float* wr = W_out + tid * HG;
        #pragma unroll 8
        for (int d = 0; d < HG; ++d) acc += wr[d] * s.hn[d];
        s.alpha[tid] = acc;   // logits
    }
    __syncthreads();
    // (d) softmax (8-wide, single thread)
    if (tid == 0) {
        float m = s.alpha[0];
        #pragma unroll
        for (int k = 1; k < KMIX; ++k) m = fmaxf(m, s.alpha[k]);
        float e[KMIX], sum = 0.f;
        #pragma unroll
        for (int k = 0; k < KMIX; ++k) { e[k] = expf(s.alpha[k] - m); sum += e[k]; }
        #pragma unroll
        for (int k = 0; k < KMIX; ++k) s.alpha[k] = e[k] / sum;
    }
    __syncthreads();
    // (e) mix
    float al[KMIX];
    #pragma unroll
    for (int k = 0; k < KMIX; ++k) al[k] = s.alpha[k];
    for (int idx = tid; idx < DZc * DZc; idx += NT) {
        float acc = 0.f;
        #pragma unroll
        for (int k = 0; k < KMIX; ++k) acc += al[k] * A_mats[k * DZc * DZc + idx];
        s.A[idx >> 6][idx & 63] = acc;
    }
    for (int idx = tid; idx < DZc * DUc; idx += NT) {
        float acc = 0.f;
        #pragma unroll
        for (int k = 0; k < KMIX; ++k) acc += al[k] * B_mats[k * DZc * DUc + idx];
        s.Bm[idx >> 3][idx & 7] = acc;
    }
    for (int idx = tid; idx < DAc * DZc; idx += NT) {
        float acc = 0.f;
        #pragma unroll
        for (int k = 0; k < KMIX; ++k) acc += al[k] * C_mats[k * DAc * DZc + idx];
        s.C[idx >> 6][idx & 63] = acc;
    }
    __syncthreads();
}

__global__ void __launch_bounds__(NT, 1)
kalman_seq(const float* __restrict__ a_seq, const float* __restrict__ h_obs,
           const float* __restrict__ u_seq, const float* __restrict__ mask,
           const float* __restrict__ A_mats, const float* __restrict__ B_mats,
           const float* __restrict__ C_mats, const float* __restrict__ a_0,
           const float* __restrict__ P_0, const float* __restrict__ Q,
           const float* __restrict__ R, const float* __restrict__ W_ih,
           const float* __restrict__ W_hh, const float* __restrict__ b_ih,
           const float* __restrict__ b_hh, const float* __restrict__ W_out,
           const float* __restrict__ b_out, float* __restrict__ out)
{
    __shared__ SMem s;
    const int b = blockIdx.x;
    const int tid = threadIdx.x;
    const int r4 = (tid >> 4) << 2;   // row base for 64-row tiles
    const int c4 = (tid & 15) << 2;   // col base for 64-col tiles
    const int r2 = (tid >> 4) << 1;   // row base for 32-row tiles
    const int c2 = (tid & 15) << 1;   // col base for 32-col tiles

    // ---------------- init ----------------
    for (int idx = tid; idx < DZc * DZc; idx += NT) {
        s.P[idx >> 6][idx & 63]  = P_0[idx];
        s.Qm[idx >> 6][idx & 63] = Q[idx];
    }
    for (int idx = tid; idx < DAc * DAc; idx += NT) s.Rm[idx >> 5][idx & 31] = R[idx];
    for (int i = tid; i < HG; i += NT) s.h[i] = 0.f;
    if (tid < DZc) s.z[tid] = 0.f;
    if (tid < DAc)                   s.x[tid] = a_0[tid];
    else if (tid < DAc + DOBSc)      s.x[tid] = h_obs[b * DOBSc + (tid - DAc)];
    else if (tid < DINc)             s.x[tid] = u_seq[(size_t)b * BT * DUc + (tid - DAc - DOBSc)];
    __syncthreads();

    // initial alpha_net + mix (alpha0 not part of outputs)
    gru_mix(s, tid, W_ih, W_hh, b_ih, b_hh, W_out, b_out, A_mats, B_mats, C_mats);

    for (int t = 0; t < BT; ++t) {
        const size_t bt = (size_t)b * BT + t;

        // phase 1: step inputs
        if (tid < DUc) { float uv = u_seq[bt * DUc + tid]; s.u[tid] = uv; s.x[DAc + DOBSc + tid] = uv; }
        if (tid < DAc) s.ak[tid] = a_seq[bt * DAc + tid];
        if (tid == 0)  s.mk = mask[bt];
        __syncthreads();
        const float mk = s.mk;

        // phase 2: zp = A z + Bm u
        if (tid < DZc) {
            float acc = 0.f;
            #pragma unroll 8
            for (int k = 0; k < DZc; ++k) acc += s.A[tid][k] * s.z[k];
            #pragma unroll
            for (int k = 0; k < DUc; ++k) acc += s.Bm[tid][k] * s.u[k];
            s.zp[tid] = acc;
        }
        __syncthreads();

        // phase 3: ahat/rvec ; CP = C @ P
        if (tid < DAc) {
            float acc = 0.f;
            #pragma unroll 8
            for (int k = 0; k < DZc; ++k) acc += s.C[tid][k] * s.zp[k];
            s.ahat[tid] = acc;
            s.rvec[tid] = s.ak[tid] - acc;
        }
        {
            float acc[2][4] = {};
            #pragma unroll 4
            for (int k = 0; k < DZc; ++k) {
                float a0 = s.C[r2][k], a1 = s.C[r2 + 1][k];
                float b0 = s.P[k][c4], b1 = s.P[k][c4 + 1], b2 = s.P[k][c4 + 2], b3 = s.P[k][c4 + 3];
                acc[0][0] += a0 * b0; acc[0][1] += a0 * b1; acc[0][2] += a0 * b2; acc[0][3] += a0 * b3;
                acc[1][0] += a1 * b0; acc[1][1] += a1 * b1; acc[1][2] += a1 * b2; acc[1][3] += a1 * b3;
            }
            #pragma unroll
            for (int i = 0; i < 2; ++i)
                #pragma unroll
                for (int j = 0; j < 4; ++j) s.CP[r2 + i][c4 + j] = acc[i][j];
        }
        __syncthreads();

        // phase 4: S = CP C^T + R ; emit S_pred
        {
            float acc[2][2] = {};
            #pragma unroll 4
            for (int k = 0; k < DZc; ++k) {
                float a0 = s.CP[r2][k], a1 = s.CP[r2 + 1][k];
                float b0 = s.C[c2][k],  b1 = s.C[c2 + 1][k];
                acc[0][0] += a0 * b0; acc[0][1] += a0 * b1;
                acc[1][0] += a1 * b0; acc[1][1] += a1 * b1;
            }
            #pragma unroll
            for (int i = 0; i < 2; ++i)
                #pragma unroll
                for (int j = 0; j < 2; ++j) {
                    float v = acc[i][j] + s.Rm[r2 + i][c2 + j];
                    s.S[r2 + i][c2 + j] = v;
                    out[O_SPRED + bt * DAc * DAc + (size_t)(r2 + i) * DAc + (c2 + j)] = v;
                }
        }
        __syncthreads();

        // phase 5: chol32 (lower) in place
        for (int k = 0; k < DAc; ++k) {
            if (tid == 0) {
                float d = sqrtf(s.S[k][k]);
                s.S[k][k] = d;
                float dinv = 1.f / d;
                for (int i = k + 1; i < DAc; ++i) s.S[i][k] *= dinv;
            }
            __syncthreads();
            int n = DAc - 1 - k;
            for (int idx = tid; idx < n * n; idx += NT) {
                int i = k + 1 + idx / n, j = k + 1 + idx % n;
                if (j <= i) s.S[i][j] -= s.S[i][k] * s.S[j][k];
            }
            __syncthreads();
        }

        // phase 6: X = S^{-1} (C P); column-parallel triangular solves (no barriers inside)
        if (tid < DZc) {
            for (int r = 0; r < DAc; ++r) {        // forward  L y = cp
                float v = s.CP[r][tid];
                for (int k = 0; k < r; ++k) v -= s.S[r][k] * s.CP[k][tid];
                s.CP[r][tid] = v / s.S[r][r];
            }
            for (int r = DAc - 1; r >= 0; --r) {   // backward L^T x = y
                float v = s.CP[r][tid];
                for (int k = r + 1; k < DAc; ++k) v -= s.S[k][r] * s.CP[k][tid];
                s.CP[r][tid] = v / s.S[r][r];
            }
        }
        __syncthreads();
        // Now Kg[i][j] = mk * CP[j][i]

        // phase 7: IKC = I - Kg C ; KR = Kg R ; zn = zp + Kg rvec
        {
            float acc[4][4] = {};
            #pragma unroll 4
            for (int k = 0; k < DAc; ++k) {
                float av[4], bv[4];
                #pragma unroll
                for (int i = 0; i < 4; ++i) av[i] = s.CP[k][r4 + i];
                #pragma unroll
                for (int j = 0; j < 4; ++j) bv[j] = s.C[k][c4 + j];
                #pragma unroll
                for (int i = 0; i < 4; ++i)
                    #pragma unroll
                    for (int j = 0; j < 4; ++j) acc[i][j] += av[i] * bv[j];
            }
            #pragma unroll
            for (int i = 0; i < 4; ++i)
                #pragma unroll
                for (int j = 0; j < 4; ++j)
                    s.IKC[r4 + i][c4 + j] = (((r4 + i) == (c4 + j)) ? 1.f : 0.f) - mk * acc[i][j];
        }
        {
            float acc[4][2] = {};
            #pragma unroll 4
            for (int k = 0; k < DAc; ++k) {
                float av[4];
                #pragma unroll
                for (int i = 0; i < 4; ++i) av[i] = s.CP[k][r4 + i];
                float b0 = s.Rm[k][c2], b1 = s.Rm[k][c2 + 1];
                #pragma unroll
                for (int i = 0; i < 4; ++i) { acc[i][0] += av[i] * b0; acc[i][1] += av[i] * b1; }
            }
            #pragma unroll
            for (int i = 0; i < 4; ++i) { s.KR[r4 + i][c2] = mk * acc[i][0]; s.KR[r4 + i][c2 + 1] = mk * acc[i][1]; }
        }
        if (tid < DZc) {
            float acc = 0.f;
            #pragma unroll 4
            for (int k = 0; k < DAc; ++k) acc += s.CP[k][tid] * s.rvec[k];
            s.zn[tid] = s.zp[tid] + mk * acc;
        }
        __syncthreads();

        // phase 8: Wk = P @ IKC^T
        {
            float acc[4][4] = {};
            #pragma unroll 4
            for (int k = 0; k < DZc; ++k) {
                float av[4], bv[4];
                #pragma unroll
                for (int i = 0; i < 4; ++i) av[i] = s.P[r4 + i][k];
                #pragma unroll
                for (int j = 0; j < 4; ++j) bv[j] = s.IKC[c4 + j][k];
                #pragma unroll
                for (int i = 0; i < 4; ++i)
                    #pragma unroll
                    for (int j = 0; j < 4; ++j) acc[i][j] += av[i] * bv[j];
            }
            #pragma unroll
            for (int i = 0; i < 4; ++i)
                #pragma unroll
                for (int j = 0; j < 4; ++j) s.Wk[r4 + i][c4 + j] = acc[i][j];
        }
        __syncthreads();

        // phase 9: raw P_filt = IKC @ Wk + mk * KR @ X   (overwrites P; reads only IKC,Wk,KR,CP)
        {
            float acc[4][4] = {};
            #pragma unroll 4
            for (int k = 0; k < DZc; ++k) {
                float av[4], bv[4];
                #pragma unroll
                for (int i = 0; i < 4; ++i) av[i] = s.IKC[r4 + i][k];
                #pragma unroll
                for (int j = 0; j < 4; ++j) bv[j] = s.Wk[k][c4 + j];
                #pragma unroll
                for (int i = 0; i < 4; ++i)
                    #pragma unroll
                    for (int j = 0; j < 4; ++j) acc[i][j] += av[i] * bv[j];
            }
            float acc2[4][4] = {};
            #pragma unroll 4
            for (int l = 0; l < DAc; ++l) {
                float av[4], bv[4];
                #pragma unroll
                for (int i = 0; i < 4; ++i) av[i] = s.KR[r4 + i][l];
                #pragma unroll
                for (int j = 0; j < 4; ++j) bv[j] = s.CP[l][c4 + j];
                #pragma unroll
                for (int i = 0; i < 4; ++i)
                    #pragma unroll
                    for (int j = 0; j < 4; ++j) acc2[i][j] += av[i] * bv[j];
            }
            #pragma unroll
            for (int i = 0; i < 4; ++i)
                #pragma unroll
                for (int j = 0; j < 4; ++j) s.P[r4 + i][c4 + j] = acc[i][j] + mk * acc2[i][j];
        }
        __syncthreads();

        // phase 10: symmetrize P_filt
        for (int idx = tid; idx < DZc * DZc; idx += NT) {
            int i = idx >> 6, j = idx & 63;
            if (i < j) {
                float v = 0.5f * (s.P[i][j] + s.P[j][i]);
                s.P[i][j] = v; s.P[j][i] = v;
            }
        }
        __syncthreads();

        // phase 11: outputs (z_filt, z_means, P_filt, a_filt, C_seq), carry z, set x[0:32]
        if (tid < DZc) {
            float v = s.zn[tid];
            out[O_ZFILT + bt * DZc + tid] = v;
            out[O_ZMEAN + bt * DZc + tid] = v;
            s.z[tid] = v;
        }
        for (int idx = tid; idx < DZc * DZc; idx += NT)
            out[O_PFILT + bt * DZc * DZc + idx] = s.P[idx >> 6][idx & 63];
        for (int idx = tid; idx < DAc * DZc; idx += NT)
            out[O_CSEQ + bt * DAc * DZc + idx] = s.C[idx >> 6][idx & 63];
        if (tid < DAc) {
            float acc = 0.f;
            #pragma unroll 8
            for (int k = 0; k < DZc; ++k) acc += s.C[tid][k] * s.zn[k];
            out[O_AFILT + bt * DAc + tid] = acc;
            s.x[tid] = mk * s.ak[tid] + (1.f - mk) * acc;   // a_k_hat
        }
        __syncthreads();

        // phases 12-16: GRU + softmax + mix  (overwrites A, Bm, C; updates h, alpha)
        gru_mix(s, tid, W_ih, W_hh, b_ih, b_hh, W_out, b_out, A_mats, B_mats, C_mats);

        // phase 17: emit alpha, A_seq, B_seq ; z_pred = A z_filt + Bm u
        if (tid < KMIX) out[O_ALPHA + bt * KMIX + tid] = s.alpha[tid];
        for (int idx = tid; idx < DZc * DZc; idx += NT)
            out[O_ASEQ + bt * DZc * DZc + idx] = s.A[idx >> 6][idx & 63];
        for (int idx = tid; idx < DZc * DUc; idx += NT)
            out[O_BSEQ + bt * DZc * DUc + idx] = s.Bm[idx >> 3][idx & 7];
        if (tid < DZc) {
            float acc = 0.f;
            #pragma unroll 8
            for (int k = 0; k < DZc; ++k) acc += s.A[tid][k] * s.z[k];
            #pragma unroll
            for (int k = 0; k < DUc; ++k) acc += s.Bm[tid][k] * s.u[k];
            s.zp[tid] = acc;
            out[O_ZPRED + bt * DZc + tid] = acc;
        }
        __syncthreads();

        // phase 18: a_pred ; Wk = A @ P_filt
        if (tid < DAc) {
            float acc = 0.f;
            #pragma unroll 8
            for (int k = 0; k < DZc; ++k) acc += s.C[tid][k] * s.zp[k];
            out[O_APRED + bt * DAc + tid] = acc;
        }
        {
            float acc[4][4] = {};
            #pragma unroll 4
            for (int k = 0; k < DZc; ++k) {
                float av[4], bv[4];
                #pragma unroll
                for (int i = 0; i < 4; ++i) av[i] = s.A[r4 + i][k];
                #pragma unroll
                for (int j = 0; j < 4; ++j) bv[j] = s.P[k][c4 + j];
                #pragma unroll
                for (int i = 0; i < 4; ++i)
                    #pragma unroll
                    for (int j = 0; j < 4; ++j) acc[i][j] += av[i] * bv[j];
            }
            #pragma unroll
            for (int i = 0; i < 4; ++i)
                #pragma unroll
                for (int j = 0; j < 4; ++j) s.Wk[r4 + i][c4 + j] = acc[i][j];
        }
        __syncthreads();

        // phase 19: raw P_pred = Wk @ A^T + Q (reads Wk, A only -> safe overwrite of P)
        {
            float acc[4][4] = {};
            #pragma unroll 4
            for (int k = 0; k < DZc; ++k) {
                float av[4], bv[4];
                #pragma unroll
                for (int i = 0; i < 4; ++i) av[i] = s.Wk[r4 + i][k];
                #pragma unroll
                for (int j = 0; j < 4; ++j) bv[j] = s.A[c4 + j][k];
                #pragma unroll
                for (int i = 0; i < 4; ++i)
                    #pragma unroll
                    for (int j = 0; j < 4; ++j) acc[i][j] += av[i] * bv[j];
            }
            #pragma unroll
            for (int i = 0; i < 4; ++i)
                #pragma unroll
                for (int j = 0; j < 4; ++j)
                    s.P[r4 + i][c4 + j] = acc[i][j] + s.Qm[r4 + i][c4 + j];
        }
        __syncthreads();

        // phase 20: symmetrize P_pred
        for (int idx = tid; idx < DZc * DZc; idx += NT) {
            int i = idx >> 6, j = idx & 63;
            if (i < j) {
                float v = 0.5f * (s.P[i][j] + s.P[j][i]);
                s.P[i][j] = v; s.P[j][i] = v;
            }
        }
        __syncthreads();

        // phase 21: emit P_pred
        for (int idx = tid; idx < DZc * DZc; idx += NT)
            out[O_PPRED + bt * DZc * DZc + idx] = s.P[idx >> 6][idx & 63];
        __syncthreads();
    }
}

// ---- kernel 2: batched 64x64 Cholesky for z_scale_tril (off the sequential path) ----
__global__ void __launch_bounds__(64, 4)
chol_batch(float* __restrict__ out)
{
    __shared__ float M[DZc][DZc + 1];
    const size_t bt = blockIdx.x;
    const int tid = threadIdx.x;
    for (int idx = tid; idx < DZc * DZc; idx += 64) {
        int i = idx >> 6, j = idx & 63;
        float v = out[O_PFILT + bt * DZc * DZc + idx];
        M[i][j] = v + ((i == j) ? 2.0e-4f : 0.f);   // P_filt already symmetric; + 2*JITTER*I
    }
    __syncthreads();
    for (int k = 0; k < DZc; ++k) {
        if (tid == 0) {
            float d = sqrtf(M[k][k]);
            M[k][k] = d;
            float dinv = 1.f / d;
            for (int i = k + 1; i < DZc; ++i) M[i][k] *= dinv;
        }
        __syncthreads();
        if (tid > k) {
            float lik = M[tid][k];
            for (int j = k + 1; j <= tid; ++j) M[tid][j] -= lik * M[j][k];
        }
        __syncthreads();
    }
    for (int idx = tid; idx < DZc * DZc; idx += 64) {
        int i = idx >> 6, j = idx & 63;
        out[O_LTRIL + bt * DZc * DZc + idx] = (j <= i) ? M[i][j] : 0.f;
    }
}

extern "C" void kernel_launch(void* const* d_in, const int* in_sizes, int n_in,
                              void* d_out, int out_size, void* d_ws, size_t ws_size,
                              hipStream_t stream) {
    const float* a_seq  = (const float*)d_in[0];
    const float* h_obs  = (const float*)d_in[1];
    const float* u_seq  = (const float*)d_in[2];
    const float* mask   = (const float*)d_in[3];
    const float* A_mats = (const float*)d_in[4];
    const float* B_mats = (const float*)d_in[5];
    const float* C_mats = (const float*)d_in[6];
    const float* a_0    = (const float*)d_in[7];
    const float* P_0    = (const float*)d_in[8];
    const float* Q      = (const float*)d_in[9];
    const float* R      = (const float*)d_in[10];
    const float* W_ih   = (const float*)d_in[11];
    const float* W_hh   = (const float*)d_in[12];
    const float* b_ih   = (const float*)d_in[13];
    const float* b_hh   = (const float*)d_in[14];
    const float* W_out  = (const float*)d_in[15];
    const float* b_out  = (const float*)d_in[16];
    float* out = (float*)d_out;

    kalman_seq<<<dim3(BB), dim3(NT), 0, stream>>>(a_seq, h_obs, u_seq, mask,
        A_mats, B_mats, C_mats, a_0, P_0, Q, R, W_ih, W_hh, b_ih, b_hh, W_out, b_out, out);
    chol_batch<<<dim3(BB * BT), dim3(64), 0, stream>>>(out);
}